// Round 14
// baseline (527.402 us; speedup 1.0000x reference)
//
#include <hip/hip_runtime.h>

constexpr int NN  = 50000;
constexpr int EE  = 800000;
constexpr int GG  = 64;
constexpr int LL  = 3;

__device__ __forceinline__ float reluf(float x) { return x > 0.f ? x : 0.f; }

// -------- in-degree count; also record each edge's within-row rank -----------
__global__ void k_count(const int* __restrict__ ei, int* __restrict__ cnt,
                        int* __restrict__ rel) {
    int e = blockIdx.x * blockDim.x + threadIdx.x;
    if (e >= EE) return;
    rel[e] = atomicAdd(&cnt[ei[EE + e]], 1);
}

// ------- parallel exclusive scan (49 blocks x 1024) + fused per-graph degmax -
__global__ void k_scan1(const int* __restrict__ cnt, int* __restrict__ off,
                        int* __restrict__ bsum,
                        const int* __restrict__ batch, const float* __restrict__ degree,
                        unsigned* __restrict__ degmax_u) {
    __shared__ int s[256];
    __shared__ unsigned smax[GG];
    int t = threadIdx.x, blk = blockIdx.x;
    if (t < GG) smax[t] = 0u;
    int base = blk * 1024 + t * 4;
    int v[4], tot = 0;
#pragma unroll
    for (int j = 0; j < 4; j++) {
        int i = base + j;
        v[j] = (i < NN) ? cnt[i] : 0;
        tot += v[j];
    }
    s[t] = tot;
    __syncthreads();
    {
        int curb = -1; unsigned cur = 0u;
#pragma unroll
        for (int j = 0; j < 4; j++) {
            int i = base + j;
            if (i < NN) {
                int b = batch[i];
                unsigned d = __float_as_uint(degree[i]);  // degree >= 0
                if (b != curb) {
                    if (curb >= 0) atomicMax(&smax[curb], cur);
                    curb = b; cur = d;
                } else if (d > cur) cur = d;
            }
        }
        if (curb >= 0) atomicMax(&smax[curb], cur);
    }
    for (int d = 1; d < 256; d <<= 1) {
        int a = (t >= d) ? s[t - d] : 0;
        __syncthreads();
        s[t] += a;
        __syncthreads();
    }
    int run = s[t] - tot;
#pragma unroll
    for (int j = 0; j < 4; j++) {
        int i = base + j;
        if (i <= NN) off[i] = run;
        run += v[j];
    }
    if (t == 255) bsum[blk] = s[255];
    __syncthreads();
    if (t < GG && smax[t] != 0u) atomicMax(&degmax_u[t], smax[t]);
}
__global__ void k_scan2(int* __restrict__ bsum, int nb) {
    if (threadIdx.x == 0) {
        int run = 0;
        for (int b = 0; b < nb; b++) { int t = bsum[b]; bsum[b] = run; run += t; }
    }
}
__global__ void k_scan3(int* __restrict__ off, const int* __restrict__ bsum) {
    int i = blockIdx.x * blockDim.x + threadIdx.x;
    if (i <= NN) off[i] += bsum[i >> 10];
}

// ---------------- scatter edges into CSR order (atomic-free) -----------------
__global__ void k_fill(const int* __restrict__ ei, const float* __restrict__ ea,
                       const int* __restrict__ off, const int* __restrict__ rel,
                       int2* __restrict__ sorted) {
    int e = blockIdx.x * blockDim.x + threadIdx.x;
    if (e >= EE) return;
    int col = ei[e];
    int row = ei[EE + e];
    sorted[off[row] + rel[e]] = make_int2(col, __float_as_int(ea[e]));
}

// ---------------- ne_sum from CSR: 8 lanes per node, 4-way unroll ------------
__global__ void k_nesum(const float* __restrict__ x, const int2* __restrict__ sorted,
                        const int* __restrict__ off, float* __restrict__ ne_sum) {
    int gwave = (blockIdx.x * blockDim.x + threadIdx.x) >> 6;
    int lane = threadIdx.x & 63;
    int sub = lane >> 3;   // 8 nodes per wave
    int f = lane & 7;      // 8 features (7 x + 1 ea)
    int node = gwave * 8 + sub;
    if (node >= NN) return;
    int jb = off[node], je = off[node + 1];
    float a0 = 0.f, a1 = 0.f, a2 = 0.f, a3 = 0.f;
    int j = jb;
    for (; j + 4 <= je; j += 4) {
        int2 p0 = sorted[j], p1 = sorted[j + 1], p2 = sorted[j + 2], p3 = sorted[j + 3];
        a0 += (f < 7) ? x[(size_t)p0.x * 7 + f] : __int_as_float(p0.y);
        a1 += (f < 7) ? x[(size_t)p1.x * 7 + f] : __int_as_float(p1.y);
        a2 += (f < 7) ? x[(size_t)p2.x * 7 + f] : __int_as_float(p2.y);
        a3 += (f < 7) ? x[(size_t)p3.x * 7 + f] : __int_as_float(p3.y);
    }
    for (; j < je; j++) {
        int2 p = sorted[j];
        a0 += (f < 7) ? x[(size_t)p.x * 7 + f] : __int_as_float(p.y);
    }
    ne_sum[(size_t)node * 8 + f] = (a0 + a1) + (a2 + a3);
}

// ---------------- node pre: x_emb and agg_in = [relu(ne@W_ene+b), degnorm] ---
__global__ __launch_bounds__(256) void k_node_pre(
        const float* __restrict__ x, const int* __restrict__ cnt,
        const float* __restrict__ ne_sum, const unsigned* __restrict__ degmax_u,
        const int* __restrict__ batch,
        const float* __restrict__ W_en, const float* __restrict__ b_en,
        const float* __restrict__ W_ene, const float* __restrict__ b_ene,
        float* __restrict__ x_emb, float* __restrict__ agg_in) {
    __shared__ float sWen[7 * 64], sben[64];
    __shared__ float sWene[8 * 63], sbene[63];
    for (int i = threadIdx.x; i < 7 * 64; i += 256) sWen[i] = W_en[i];
    for (int i = threadIdx.x; i < 64; i += 256) sben[i] = b_en[i];
    for (int i = threadIdx.x; i < 8 * 63; i += 256) sWene[i] = W_ene[i];
    for (int i = threadIdx.x; i < 63; i += 256) sbene[i] = b_ene[i];
    __syncthreads();
    int lane = threadIdx.x & 63;
    int slot = threadIdx.x >> 6;
    int wave = blockIdx.x * 4 + slot;
    int nw = gridDim.x * 4;
    for (int i = wave; i < NN; i += nw) {
        float acc = sben[lane];
#pragma unroll
        for (int k = 0; k < 7; k++) acc += x[(size_t)i * 7 + k] * sWen[k * 64 + lane];
        x_emb[(size_t)i * 64 + lane] = reluf(acc);
        float c = (float)cnt[i]; if (c < 1.f) c = 1.f;
        float rc = 1.f / c;
        int oo = lane < 63 ? lane : 0;
        float na = sbene[oo];
#pragma unroll
        for (int k = 0; k < 8; k++) na += (ne_sum[(size_t)i * 8 + k] * rc) * sWene[k * 63 + oo];
        na = reluf(na);
        float dn = __uint_as_float(degmax_u[batch[i]]);
        agg_in[(size_t)i * 64 + lane] = (lane < 63) ? na : dn;
    }
}

// ---------------- half-K matvec pass with LDS-staged input (r13 proven) ------
// MODE 0: out = dot   MODE 1: out = relu(dot + tmp + b)   MODE 2: relu(dot + b)
template <int MODE>
__global__ __launch_bounds__(256) void k_mv64(
        const float* __restrict__ in, const float* __restrict__ W,
        const float* __restrict__ b, const float* __restrict__ tmp,
        float* __restrict__ out, int nwaves) {
    __shared__ float sbuf[4][2][64];
    int slot = threadIdx.x >> 6;
    int gwave = (blockIdx.x * blockDim.x + threadIdx.x) >> 6;
    int lane = threadIdx.x & 63;
    int per = (NN + nwaves - 1) / nwaves;
    int n0 = gwave * per;
    int n1 = n0 + per; if (n1 > NN) n1 = NN;
    if (n0 >= n1) return;
    float w[64];
#pragma unroll
    for (int k = 0; k < 64; k++) w[k] = W[(size_t)k * 64 + lane];
    float bias = (MODE == 0) ? 0.f : b[lane];
    sbuf[slot][0][lane] = in[(size_t)n0 * 64 + lane];
    int cntn = n1 - n0;
    for (int i = 0; i < cntn; i++) {
        int n = n0 + i;
        size_t oA = (size_t)n * 64 + lane;
        float tv = (MODE == 1) ? tmp[oA] : 0.f;
        float vnext = 0.f;
        if (i + 1 < cntn) vnext = in[(size_t)(n + 1) * 64 + lane];
        const float* bufp = &sbuf[slot][i & 1][0];
        float a0 = 0.f, a1 = 0.f;
#pragma unroll
        for (int kb = 0; kb < 64; kb += 8) {
            float4 x0 = *(const float4*)(bufp + kb);
            float4 x1 = *(const float4*)(bufp + kb + 4);
            a0 = fmaf(x0.x, w[kb + 0], a0); a1 = fmaf(x0.y, w[kb + 1], a1);
            a0 = fmaf(x0.z, w[kb + 2], a0); a1 = fmaf(x0.w, w[kb + 3], a1);
            a0 = fmaf(x1.x, w[kb + 4], a0); a1 = fmaf(x1.y, w[kb + 5], a1);
            a0 = fmaf(x1.z, w[kb + 6], a0); a1 = fmaf(x1.w, w[kb + 7], a1);
        }
        float r = a0 + a1;
        if (MODE == 0)      out[oA] = r;
        else if (MODE == 1) out[oA] = reluf(r + tv + bias);
        else                out[oA] = reluf(r + bias);
        if (i + 1 < cntn) sbuf[slot][(i + 1) & 1][lane] = vnext;
    }
}

// ------ fused: x_agg row (gather-mean) -> LDS -> dot with WmA -> tmpb --------
// Agg part is the proven 8-way-unrolled gather (lane = feature). The computed
// row is staged in wave-private LDS (no barrier; same-wave DS ordering) and
// immediately multiplied against the preloaded WmA column (lane = output).
// Eliminates the xagg global round-trip and 3 k_mv64<0> dispatches.
__global__ void k_agg_mv(
        const float* __restrict__ xemb, const int* __restrict__ off,
        const int* __restrict__ cnt, const int2* __restrict__ sorted,
        const float* __restrict__ W, float* __restrict__ tmpb) {
    __shared__ float srow[4][64];
    int lane = threadIdx.x & 63;
    int slot = threadIdx.x >> 6;
    int wave = blockIdx.x * 4 + slot;
    int nw = gridDim.x * 4;
    float w[64];
#pragma unroll
    for (int k = 0; k < 64; k++) w[k] = W[(size_t)k * 64 + lane];
    for (int i = wave; i < NN; i += nw) {
        int jb = off[i], je = off[i + 1];
        float a0 = 0.f, a1 = 0.f, a2 = 0.f, a3 = 0.f;
        float a4 = 0.f, a5 = 0.f, a6 = 0.f, a7 = 0.f;
        int j = jb;
        for (; j + 8 <= je; j += 8) {
            int2 p0 = sorted[j + 0], p1 = sorted[j + 1];
            int2 p2 = sorted[j + 2], p3 = sorted[j + 3];
            int2 p4 = sorted[j + 4], p5 = sorted[j + 5];
            int2 p6 = sorted[j + 6], p7 = sorted[j + 7];
            a0 = fmaf(__int_as_float(p0.y), xemb[(size_t)p0.x * 64 + lane], a0);
            a1 = fmaf(__int_as_float(p1.y), xemb[(size_t)p1.x * 64 + lane], a1);
            a2 = fmaf(__int_as_float(p2.y), xemb[(size_t)p2.x * 64 + lane], a2);
            a3 = fmaf(__int_as_float(p3.y), xemb[(size_t)p3.x * 64 + lane], a3);
            a4 = fmaf(__int_as_float(p4.y), xemb[(size_t)p4.x * 64 + lane], a4);
            a5 = fmaf(__int_as_float(p5.y), xemb[(size_t)p5.x * 64 + lane], a5);
            a6 = fmaf(__int_as_float(p6.y), xemb[(size_t)p6.x * 64 + lane], a6);
            a7 = fmaf(__int_as_float(p7.y), xemb[(size_t)p7.x * 64 + lane], a7);
        }
        for (; j < je; j++) {
            int2 p = sorted[j];
            a0 = fmaf(__int_as_float(p.y), xemb[(size_t)p.x * 64 + lane], a0);
        }
        float acc = ((a0 + a1) + (a2 + a3)) + ((a4 + a5) + (a6 + a7));
        float c = (float)cnt[i]; if (c < 1.f) c = 1.f;
        srow[slot][lane] = acc * (1.f / c);   // wave-private; no barrier needed
        const float* bufp = &srow[slot][0];
        float d0 = 0.f, d1 = 0.f;
#pragma unroll
        for (int kb = 0; kb < 64; kb += 8) {
            float4 x0 = *(const float4*)(bufp + kb);
            float4 x1 = *(const float4*)(bufp + kb + 4);
            d0 = fmaf(x0.x, w[kb + 0], d0); d1 = fmaf(x0.y, w[kb + 1], d1);
            d0 = fmaf(x0.z, w[kb + 2], d0); d1 = fmaf(x0.w, w[kb + 3], d1);
            d0 = fmaf(x1.x, w[kb + 4], d0); d1 = fmaf(x1.y, w[kb + 5], d1);
            d0 = fmaf(x1.z, w[kb + 6], d0); d1 = fmaf(x1.w, w[kb + 7], d1);
        }
        tmpb[(size_t)i * 64 + lane] = d0 + d1;
    }
}

// ---------------- graph mean (batch sorted: chunked accumulation) ------------
constexpr int CHUNK = 32;
__global__ void k_graph_sum(const float* __restrict__ xemb, const int* __restrict__ batch,
                            float* __restrict__ g_sum, int* __restrict__ g_cnt) {
    int wave = (blockIdx.x * blockDim.x + threadIdx.x) >> 6;
    int lane = threadIdx.x & 63;
    int i0 = wave * CHUNK;
    if (i0 >= NN) return;
    int i1 = i0 + CHUNK; if (i1 > NN) i1 = NN;
    int curb = batch[i0];
    float acc = 0.f;
    int ncnt = 0;
    for (int i = i0; i < i1; i++) {
        int b = batch[i];
        if (b != curb) {
            unsafeAtomicAdd(&g_sum[curb * 64 + lane], acc);
            if (lane == 0) atomicAdd(&g_cnt[curb], ncnt);
            acc = 0.f; ncnt = 0; curb = b;
        }
        acc += xemb[(size_t)i * 64 + lane];
        ncnt++;
    }
    unsafeAtomicAdd(&g_sum[curb * 64 + lane], acc);
    if (lane == 0) atomicAdd(&g_cnt[curb], ncnt);
}

// ---------------- graph embedding: g_agg = mean @ W_g + b_g (no relu) --------
__global__ void k_graph_emb(const float* __restrict__ g_sum, const int* __restrict__ g_cnt,
                            const float* __restrict__ W_g, const float* __restrict__ b_g,
                            float* __restrict__ g_agg) {
    __shared__ float sin[4 * 64];
    int lane = threadIdx.x & 63;
    int slot = threadIdx.x >> 6;
    int g = blockIdx.x * 4 + slot;
    if (g >= GG) return;
    float c = (float)g_cnt[g]; if (c < 1.f) c = 1.f;
    sin[slot * 64 + lane] = g_sum[g * 64 + lane] * (1.f / c);
    __syncthreads();
    float acc = b_g[lane];
    for (int k = 0; k < 64; k++) acc += sin[slot * 64 + k] * W_g[k * 64 + lane];
    g_agg[g * 64 + lane] = acc;
}

// ---------------- readout: q = relu([g_agg[batch], x_emb]) @ W_r + b_r -------
__global__ void k_readout(const float* __restrict__ g_agg, const float* __restrict__ xemb,
                          const int* __restrict__ batch,
                          const float* __restrict__ W_r, const float* __restrict__ b_r,
                          float* __restrict__ out) {
    int i = blockIdx.x * blockDim.x + threadIdx.x;
    if (i >= NN) return;
    int b = batch[i];
    float acc = b_r[0];
    const float* ga = g_agg + (size_t)b * 64;
    const float* xe = xemb + (size_t)i * 64;
#pragma unroll 8
    for (int k = 0; k < 64; k++) acc += reluf(ga[k]) * W_r[k];
#pragma unroll 8
    for (int k = 0; k < 64; k++) acc += reluf(xe[k]) * W_r[64 + k];
    out[i] = acc;
}

extern "C" void kernel_launch(void* const* d_in, const int* in_sizes, int n_in,
                              void* d_out, int out_size, void* d_ws, size_t ws_size,
                              hipStream_t stream) {
    const float* x      = (const float*)d_in[0];
    const int*   ei     = (const int*)d_in[1];
    const float* ea     = (const float*)d_in[2];
    const int*   batch  = (const int*)d_in[3];
    const float* degree = (const float*)d_in[4];
    const float* W_en  = (const float*)d_in[6];
    const float* b_en  = (const float*)d_in[7];
    const float* W_ene = (const float*)d_in[8];
    const float* b_ene = (const float*)d_in[9];
    const float* W_agg = (const float*)d_in[10];
    const float* b_agg = (const float*)d_in[11];
    const float* Wm    = (const float*)d_in[12];
    const float* bm    = (const float*)d_in[13];
    const float* Wu    = (const float*)d_in[14];
    const float* bu    = (const float*)d_in[15];
    const float* W_g   = (const float*)d_in[16];
    const float* b_g   = (const float*)d_in[17];
    const float* W_r   = (const float*)d_in[18];
    const float* b_r   = (const float*)d_in[19];
    float* out = (float*)d_out;

    // workspace layout (4B element offsets); zeroed region first
    char* ws = (char*)d_ws;
    size_t o = 0;
    int*      cnt      = (int*)(ws + o * 4);      o += NN;
    unsigned* degmax_u = (unsigned*)(ws + o * 4); o += GG;
    float*    g_sum    = (float*)(ws + o * 4);    o += GG * 64;
    int*      g_cnt    = (int*)(ws + o * 4);      o += GG;
    size_t zero_bytes = o * 4;
    int*      off      = (int*)(ws + o * 4);      o += NN + 1;
    int*      bsum     = (int*)(ws + o * 4);      o += 64;
    int*      rel      = (int*)(ws + o * 4);      o += EE;
    float*    ne_sum   = (float*)(ws + o * 4);    o += (size_t)NN * 8;
    o = (o + 1) & ~(size_t)1;  // 8B-align for int2
    int2*     sorted   = (int2*)(ws + o * 4);     o += (size_t)EE * 2;
    float*    agg_in   = (float*)(ws + o * 4);    o += (size_t)NN * 64;
    float*    xae      = (float*)(ws + o * 4);    o += (size_t)NN * 64;
    float*    xA       = (float*)(ws + o * 4);    o += (size_t)NN * 64;
    float*    xB       = (float*)(ws + o * 4);    o += (size_t)NN * 64;
    float*    mbuf     = (float*)(ws + o * 4);    o += (size_t)NN * 64;
    float*    tmpb     = (float*)(ws + o * 4);    o += (size_t)NN * 64;
    float*    g_agg    = (float*)(ws + o * 4);    o += GG * 64;

    hipMemsetAsync(d_ws, 0, zero_bytes, stream);

    const int NB_SCAN = 49;        // ceil(50001/1024)
    const int MV_BLOCKS = 1024;    // 4096 waves, ~13 nodes/wave
    const int MV_WAVES = MV_BLOCKS * 4;
    k_count<<<(EE + 255) / 256, 256, 0, stream>>>(ei, cnt, rel);
    k_scan1<<<NB_SCAN, 256, 0, stream>>>(cnt, off, bsum, batch, degree, degmax_u);
    k_scan2<<<1, 64, 0, stream>>>(bsum, NB_SCAN);
    k_scan3<<<(NN + 256) / 256, 256, 0, stream>>>(off, bsum);
    k_fill<<<(EE + 255) / 256, 256, 0, stream>>>(ei, ea, off, rel, sorted);
    k_nesum<<<((NN + 7) / 8 * 64 + 255) / 256, 256, 0, stream>>>(x, sorted, off, ne_sum);
    k_node_pre<<<512, 256, 0, stream>>>(x, cnt, ne_sum, degmax_u, batch,
                                        W_en, b_en, W_ene, b_ene, xA, agg_in);
    // x_agg_emb = relu(agg_in @ W_agg + b_agg)   (K=64, standalone)
    k_mv64<2><<<MV_BLOCKS, 256, 0, stream>>>(agg_in, W_agg, b_agg, nullptr, xae, MV_WAVES);
    const float* cur = xA;
    float* nxt = xB;
    for (int l = 0; l < LL; l++) {
        const float* WmL = Wm + (size_t)l * 128 * 64;
        const float* WuL = Wu + (size_t)l * 128 * 64;
        // fused: gather-mean + (xagg @ WmA) -> tmpb
        k_agg_mv<<<2048, 256, 0, stream>>>(cur, off, cnt, sorted, WmL, tmpb);
        // m = relu(tmpb + xae @ WmB + bm)
        k_mv64<1><<<MV_BLOCKS, 256, 0, stream>>>(xae, WmL + 64 * 64, bm + l * 64, tmpb,
                                                 mbuf, MV_WAVES);
        // x' = relu([xemb|m] @ Wu + bu)  as two K=64 passes
        k_mv64<0><<<MV_BLOCKS, 256, 0, stream>>>(cur, WuL, nullptr, nullptr, tmpb, MV_WAVES);
        k_mv64<1><<<MV_BLOCKS, 256, 0, stream>>>(mbuf, WuL + 64 * 64, bu + l * 64, tmpb,
                                                 nxt, MV_WAVES);
        float* t = (float*)cur; cur = nxt; nxt = t;
    }
    int gs_waves = (NN + CHUNK - 1) / CHUNK;
    k_graph_sum<<<(gs_waves * 64 + 255) / 256, 256, 0, stream>>>(cur, batch, g_sum, g_cnt);
    k_graph_emb<<<16, 256, 0, stream>>>(g_sum, g_cnt, W_g, b_g, g_agg);
    k_readout<<<(NN + 255) / 256, 256, 0, stream>>>(g_agg, cur, batch, W_r, b_r, out);
}

// Round 15
// 510.480 us; speedup vs baseline: 1.0331x; 1.0331x over previous
//
#include <hip/hip_runtime.h>

constexpr int NN  = 50000;
constexpr int EE  = 800000;
constexpr int GG  = 64;
constexpr int LL  = 3;

__device__ __forceinline__ float reluf(float x) { return x > 0.f ? x : 0.f; }

// -------- in-degree count; also record each edge's within-row rank -----------
__global__ void k_count(const int* __restrict__ ei, int* __restrict__ cnt,
                        int* __restrict__ rel) {
    int e = blockIdx.x * blockDim.x + threadIdx.x;
    if (e >= EE) return;
    rel[e] = atomicAdd(&cnt[ei[EE + e]], 1);
}

// ------- parallel exclusive scan (49 blocks x 1024) + fused per-graph degmax -
__global__ void k_scan1(const int* __restrict__ cnt, int* __restrict__ off,
                        int* __restrict__ bsum,
                        const int* __restrict__ batch, const float* __restrict__ degree,
                        unsigned* __restrict__ degmax_u) {
    __shared__ int s[256];
    __shared__ unsigned smax[GG];
    int t = threadIdx.x, blk = blockIdx.x;
    if (t < GG) smax[t] = 0u;
    int base = blk * 1024 + t * 4;
    int v[4], tot = 0;
#pragma unroll
    for (int j = 0; j < 4; j++) {
        int i = base + j;
        v[j] = (i < NN) ? cnt[i] : 0;
        tot += v[j];
    }
    s[t] = tot;
    __syncthreads();
    {
        int curb = -1; unsigned cur = 0u;
#pragma unroll
        for (int j = 0; j < 4; j++) {
            int i = base + j;
            if (i < NN) {
                int b = batch[i];
                unsigned d = __float_as_uint(degree[i]);  // degree >= 0
                if (b != curb) {
                    if (curb >= 0) atomicMax(&smax[curb], cur);
                    curb = b; cur = d;
                } else if (d > cur) cur = d;
            }
        }
        if (curb >= 0) atomicMax(&smax[curb], cur);
    }
    for (int d = 1; d < 256; d <<= 1) {
        int a = (t >= d) ? s[t - d] : 0;
        __syncthreads();
        s[t] += a;
        __syncthreads();
    }
    int run = s[t] - tot;
#pragma unroll
    for (int j = 0; j < 4; j++) {
        int i = base + j;
        if (i <= NN) off[i] = run;
        run += v[j];
    }
    if (t == 255) bsum[blk] = s[255];
    __syncthreads();
    if (t < GG && smax[t] != 0u) atomicMax(&degmax_u[t], smax[t]);
}
__global__ void k_scan2(int* __restrict__ bsum, int nb) {
    if (threadIdx.x == 0) {
        int run = 0;
        for (int b = 0; b < nb; b++) { int t = bsum[b]; bsum[b] = run; run += t; }
    }
}
__global__ void k_scan3(int* __restrict__ off, const int* __restrict__ bsum) {
    int i = blockIdx.x * blockDim.x + threadIdx.x;
    if (i <= NN) off[i] += bsum[i >> 10];
}

// ---------------- scatter edges into CSR order (atomic-free) -----------------
__global__ void k_fill(const int* __restrict__ ei, const float* __restrict__ ea,
                       const int* __restrict__ off, const int* __restrict__ rel,
                       int2* __restrict__ sorted) {
    int e = blockIdx.x * blockDim.x + threadIdx.x;
    if (e >= EE) return;
    int col = ei[e];
    int row = ei[EE + e];
    sorted[off[row] + rel[e]] = make_int2(col, __float_as_int(ea[e]));
}

// ---------------- ne_sum from CSR: 8 lanes per node, 4-way unroll ------------
__global__ void k_nesum(const float* __restrict__ x, const int2* __restrict__ sorted,
                        const int* __restrict__ off, float* __restrict__ ne_sum) {
    int gwave = (blockIdx.x * blockDim.x + threadIdx.x) >> 6;
    int lane = threadIdx.x & 63;
    int sub = lane >> 3;   // 8 nodes per wave
    int f = lane & 7;      // 8 features (7 x + 1 ea)
    int node = gwave * 8 + sub;
    if (node >= NN) return;
    int jb = off[node], je = off[node + 1];
    float a0 = 0.f, a1 = 0.f, a2 = 0.f, a3 = 0.f;
    int j = jb;
    for (; j + 4 <= je; j += 4) {
        int2 p0 = sorted[j], p1 = sorted[j + 1], p2 = sorted[j + 2], p3 = sorted[j + 3];
        a0 += (f < 7) ? x[(size_t)p0.x * 7 + f] : __int_as_float(p0.y);
        a1 += (f < 7) ? x[(size_t)p1.x * 7 + f] : __int_as_float(p1.y);
        a2 += (f < 7) ? x[(size_t)p2.x * 7 + f] : __int_as_float(p2.y);
        a3 += (f < 7) ? x[(size_t)p3.x * 7 + f] : __int_as_float(p3.y);
    }
    for (; j < je; j++) {
        int2 p = sorted[j];
        a0 += (f < 7) ? x[(size_t)p.x * 7 + f] : __int_as_float(p.y);
    }
    ne_sum[(size_t)node * 8 + f] = (a0 + a1) + (a2 + a3);
}

// ---------------- node pre: x_emb and agg_in = [relu(ne@W_ene+b), degnorm] ---
__global__ __launch_bounds__(256) void k_node_pre(
        const float* __restrict__ x, const int* __restrict__ cnt,
        const float* __restrict__ ne_sum, const unsigned* __restrict__ degmax_u,
        const int* __restrict__ batch,
        const float* __restrict__ W_en, const float* __restrict__ b_en,
        const float* __restrict__ W_ene, const float* __restrict__ b_ene,
        float* __restrict__ x_emb, float* __restrict__ agg_in) {
    __shared__ float sWen[7 * 64], sben[64];
    __shared__ float sWene[8 * 63], sbene[63];
    for (int i = threadIdx.x; i < 7 * 64; i += 256) sWen[i] = W_en[i];
    for (int i = threadIdx.x; i < 64; i += 256) sben[i] = b_en[i];
    for (int i = threadIdx.x; i < 8 * 63; i += 256) sWene[i] = W_ene[i];
    for (int i = threadIdx.x; i < 63; i += 256) sbene[i] = b_ene[i];
    __syncthreads();
    int lane = threadIdx.x & 63;
    int slot = threadIdx.x >> 6;
    int wave = blockIdx.x * 4 + slot;
    int nw = gridDim.x * 4;
    for (int i = wave; i < NN; i += nw) {
        float acc = sben[lane];
#pragma unroll
        for (int k = 0; k < 7; k++) acc += x[(size_t)i * 7 + k] * sWen[k * 64 + lane];
        x_emb[(size_t)i * 64 + lane] = reluf(acc);
        float c = (float)cnt[i]; if (c < 1.f) c = 1.f;
        float rc = 1.f / c;
        int oo = lane < 63 ? lane : 0;
        float na = sbene[oo];
#pragma unroll
        for (int k = 0; k < 8; k++) na += (ne_sum[(size_t)i * 8 + k] * rc) * sWene[k * 63 + oo];
        na = reluf(na);
        float dn = __uint_as_float(degmax_u[batch[i]]);
        agg_in[(size_t)i * 64 + lane] = (lane < 63) ? na : dn;
    }
}

// ---------------- half-K matvec pass with LDS-staged input (r13 proven) ------
// Weight-stationary w[64] in VGPRs; wave-private LDS double buffer for the
// broadcast input row (vector-pipe staging, no barriers). 3072 waves:
// fewer/longer waves than r13's 4096 to amortize the 16KB/wave weight
// preload and per-wave ramp over more nodes.
// MODE 0: out = dot   MODE 1: out = relu(dot + tmp + b)   MODE 2: relu(dot + b)
template <int MODE>
__global__ __launch_bounds__(256) void k_mv64(
        const float* __restrict__ in, const float* __restrict__ W,
        const float* __restrict__ b, const float* __restrict__ tmp,
        float* __restrict__ out, int nwaves) {
    __shared__ float sbuf[4][2][64];
    int slot = threadIdx.x >> 6;
    int gwave = (blockIdx.x * blockDim.x + threadIdx.x) >> 6;
    int lane = threadIdx.x & 63;
    int per = (NN + nwaves - 1) / nwaves;
    int n0 = gwave * per;
    int n1 = n0 + per; if (n1 > NN) n1 = NN;
    if (n0 >= n1) return;
    float w[64];
#pragma unroll
    for (int k = 0; k < 64; k++) w[k] = W[(size_t)k * 64 + lane];
    float bias = (MODE == 0) ? 0.f : b[lane];
    sbuf[slot][0][lane] = in[(size_t)n0 * 64 + lane];
    int cntn = n1 - n0;
    for (int i = 0; i < cntn; i++) {
        int n = n0 + i;
        size_t oA = (size_t)n * 64 + lane;
        float tv = (MODE == 1) ? tmp[oA] : 0.f;
        float vnext = 0.f;
        if (i + 1 < cntn) vnext = in[(size_t)(n + 1) * 64 + lane];
        const float* bufp = &sbuf[slot][i & 1][0];
        float a0 = 0.f, a1 = 0.f;
#pragma unroll
        for (int kb = 0; kb < 64; kb += 8) {
            float4 x0 = *(const float4*)(bufp + kb);
            float4 x1 = *(const float4*)(bufp + kb + 4);
            a0 = fmaf(x0.x, w[kb + 0], a0); a1 = fmaf(x0.y, w[kb + 1], a1);
            a0 = fmaf(x0.z, w[kb + 2], a0); a1 = fmaf(x0.w, w[kb + 3], a1);
            a0 = fmaf(x1.x, w[kb + 4], a0); a1 = fmaf(x1.y, w[kb + 5], a1);
            a0 = fmaf(x1.z, w[kb + 6], a0); a1 = fmaf(x1.w, w[kb + 7], a1);
        }
        float r = a0 + a1;
        if (MODE == 0)      out[oA] = r;
        else if (MODE == 1) out[oA] = reluf(r + tv + bias);
        else                out[oA] = reluf(r + bias);
        if (i + 1 < cntn) sbuf[slot][(i + 1) & 1][lane] = vnext;
    }
}

// -------- layer aggregation: x_agg = mean_j ea_j * xemb[col_j] ---------------
// 8-way unroll: 8 independent gathers in flight per wave (r6-proven).
__global__ __launch_bounds__(256) void k_layer_agg(
        const float* __restrict__ xemb, const int* __restrict__ off,
        const int* __restrict__ cnt, const int2* __restrict__ sorted,
        float* __restrict__ xagg) {
    int lane = threadIdx.x & 63;
    int slot = threadIdx.x >> 6;
    int wave = blockIdx.x * 4 + slot;
    int nw = gridDim.x * 4;
    for (int i = wave; i < NN; i += nw) {
        int jb = off[i], je = off[i + 1];
        float a0 = 0.f, a1 = 0.f, a2 = 0.f, a3 = 0.f;
        float a4 = 0.f, a5 = 0.f, a6 = 0.f, a7 = 0.f;
        int j = jb;
        for (; j + 8 <= je; j += 8) {
            int2 p0 = sorted[j + 0], p1 = sorted[j + 1];
            int2 p2 = sorted[j + 2], p3 = sorted[j + 3];
            int2 p4 = sorted[j + 4], p5 = sorted[j + 5];
            int2 p6 = sorted[j + 6], p7 = sorted[j + 7];
            a0 = fmaf(__int_as_float(p0.y), xemb[(size_t)p0.x * 64 + lane], a0);
            a1 = fmaf(__int_as_float(p1.y), xemb[(size_t)p1.x * 64 + lane], a1);
            a2 = fmaf(__int_as_float(p2.y), xemb[(size_t)p2.x * 64 + lane], a2);
            a3 = fmaf(__int_as_float(p3.y), xemb[(size_t)p3.x * 64 + lane], a3);
            a4 = fmaf(__int_as_float(p4.y), xemb[(size_t)p4.x * 64 + lane], a4);
            a5 = fmaf(__int_as_float(p5.y), xemb[(size_t)p5.x * 64 + lane], a5);
            a6 = fmaf(__int_as_float(p6.y), xemb[(size_t)p6.x * 64 + lane], a6);
            a7 = fmaf(__int_as_float(p7.y), xemb[(size_t)p7.x * 64 + lane], a7);
        }
        for (; j < je; j++) {
            int2 p = sorted[j];
            a0 = fmaf(__int_as_float(p.y), xemb[(size_t)p.x * 64 + lane], a0);
        }
        float acc = ((a0 + a1) + (a2 + a3)) + ((a4 + a5) + (a6 + a7));
        float c = (float)cnt[i]; if (c < 1.f) c = 1.f;
        xagg[(size_t)i * 64 + lane] = acc * (1.f / c);
    }
}

// ---------------- graph mean (batch sorted: chunked accumulation) ------------
constexpr int CHUNK = 32;
__global__ void k_graph_sum(const float* __restrict__ xemb, const int* __restrict__ batch,
                            float* __restrict__ g_sum, int* __restrict__ g_cnt) {
    int wave = (blockIdx.x * blockDim.x + threadIdx.x) >> 6;
    int lane = threadIdx.x & 63;
    int i0 = wave * CHUNK;
    if (i0 >= NN) return;
    int i1 = i0 + CHUNK; if (i1 > NN) i1 = NN;
    int curb = batch[i0];
    float acc = 0.f;
    int ncnt = 0;
    for (int i = i0; i < i1; i++) {
        int b = batch[i];
        if (b != curb) {
            unsafeAtomicAdd(&g_sum[curb * 64 + lane], acc);
            if (lane == 0) atomicAdd(&g_cnt[curb], ncnt);
            acc = 0.f; ncnt = 0; curb = b;
        }
        acc += xemb[(size_t)i * 64 + lane];
        ncnt++;
    }
    unsafeAtomicAdd(&g_sum[curb * 64 + lane], acc);
    if (lane == 0) atomicAdd(&g_cnt[curb], ncnt);
}

// ---------------- graph embedding: g_agg = mean @ W_g + b_g (no relu) --------
__global__ void k_graph_emb(const float* __restrict__ g_sum, const int* __restrict__ g_cnt,
                            const float* __restrict__ W_g, const float* __restrict__ b_g,
                            float* __restrict__ g_agg) {
    __shared__ float sin[4 * 64];
    int lane = threadIdx.x & 63;
    int slot = threadIdx.x >> 6;
    int g = blockIdx.x * 4 + slot;
    if (g >= GG) return;
    float c = (float)g_cnt[g]; if (c < 1.f) c = 1.f;
    sin[slot * 64 + lane] = g_sum[g * 64 + lane] * (1.f / c);
    __syncthreads();
    float acc = b_g[lane];
    for (int k = 0; k < 64; k++) acc += sin[slot * 64 + k] * W_g[k * 64 + lane];
    g_agg[g * 64 + lane] = acc;
}

// ---------------- readout: q = relu([g_agg[batch], x_emb]) @ W_r + b_r -------
__global__ void k_readout(const float* __restrict__ g_agg, const float* __restrict__ xemb,
                          const int* __restrict__ batch,
                          const float* __restrict__ W_r, const float* __restrict__ b_r,
                          float* __restrict__ out) {
    int i = blockIdx.x * blockDim.x + threadIdx.x;
    if (i >= NN) return;
    int b = batch[i];
    float acc = b_r[0];
    const float* ga = g_agg + (size_t)b * 64;
    const float* xe = xemb + (size_t)i * 64;
#pragma unroll 8
    for (int k = 0; k < 64; k++) acc += reluf(ga[k]) * W_r[k];
#pragma unroll 8
    for (int k = 0; k < 64; k++) acc += reluf(xe[k]) * W_r[64 + k];
    out[i] = acc;
}

extern "C" void kernel_launch(void* const* d_in, const int* in_sizes, int n_in,
                              void* d_out, int out_size, void* d_ws, size_t ws_size,
                              hipStream_t stream) {
    const float* x      = (const float*)d_in[0];
    const int*   ei     = (const int*)d_in[1];
    const float* ea     = (const float*)d_in[2];
    const int*   batch  = (const int*)d_in[3];
    const float* degree = (const float*)d_in[4];
    const float* W_en  = (const float*)d_in[6];
    const float* b_en  = (const float*)d_in[7];
    const float* W_ene = (const float*)d_in[8];
    const float* b_ene = (const float*)d_in[9];
    const float* W_agg = (const float*)d_in[10];
    const float* b_agg = (const float*)d_in[11];
    const float* Wm    = (const float*)d_in[12];
    const float* bm    = (const float*)d_in[13];
    const float* Wu    = (const float*)d_in[14];
    const float* bu    = (const float*)d_in[15];
    const float* W_g   = (const float*)d_in[16];
    const float* b_g   = (const float*)d_in[17];
    const float* W_r   = (const float*)d_in[18];
    const float* b_r   = (const float*)d_in[19];
    float* out = (float*)d_out;

    // workspace layout (4B element offsets); zeroed region first
    char* ws = (char*)d_ws;
    size_t o = 0;
    int*      cnt      = (int*)(ws + o * 4);      o += NN;
    unsigned* degmax_u = (unsigned*)(ws + o * 4); o += GG;
    float*    g_sum    = (float*)(ws + o * 4);    o += GG * 64;
    int*      g_cnt    = (int*)(ws + o * 4);      o += GG;
    size_t zero_bytes = o * 4;
    int*      off      = (int*)(ws + o * 4);      o += NN + 1;
    int*      bsum     = (int*)(ws + o * 4);      o += 64;
    int*      rel      = (int*)(ws + o * 4);      o += EE;
    float*    ne_sum   = (float*)(ws + o * 4);    o += (size_t)NN * 8;
    o = (o + 1) & ~(size_t)1;  // 8B-align for int2
    int2*     sorted   = (int2*)(ws + o * 4);     o += (size_t)EE * 2;
    float*    agg_in   = (float*)(ws + o * 4);    o += (size_t)NN * 64;
    float*    xae      = (float*)(ws + o * 4);    o += (size_t)NN * 64;
    float*    xA       = (float*)(ws + o * 4);    o += (size_t)NN * 64;
    float*    xB       = (float*)(ws + o * 4);    o += (size_t)NN * 64;
    float*    xagg     = (float*)(ws + o * 4);    o += (size_t)NN * 64;
    float*    mbuf     = (float*)(ws + o * 4);    o += (size_t)NN * 64;
    float*    tmpb     = (float*)(ws + o * 4);    o += (size_t)NN * 64;
    float*    g_agg    = (float*)(ws + o * 4);    o += GG * 64;

    hipMemsetAsync(d_ws, 0, zero_bytes, stream);

    const int NB_SCAN = 49;       // ceil(50001/1024)
    const int MV_BLOCKS = 768;    // 3072 waves, ~17 nodes/wave
    const int MV_WAVES = MV_BLOCKS * 4;
    k_count<<<(EE + 255) / 256, 256, 0, stream>>>(ei, cnt, rel);
    k_scan1<<<NB_SCAN, 256, 0, stream>>>(cnt, off, bsum, batch, degree, degmax_u);
    k_scan2<<<1, 64, 0, stream>>>(bsum, NB_SCAN);
    k_scan3<<<(NN + 256) / 256, 256, 0, stream>>>(off, bsum);
    k_fill<<<(EE + 255) / 256, 256, 0, stream>>>(ei, ea, off, rel, sorted);
    k_nesum<<<((NN + 7) / 8 * 64 + 255) / 256, 256, 0, stream>>>(x, sorted, off, ne_sum);
    k_node_pre<<<512, 256, 0, stream>>>(x, cnt, ne_sum, degmax_u, batch,
                                        W_en, b_en, W_ene, b_ene, xA, agg_in);
    // x_agg_emb = relu(agg_in @ W_agg + b_agg)   (K=64, standalone)
    k_mv64<2><<<MV_BLOCKS, 256, 0, stream>>>(agg_in, W_agg, b_agg, nullptr, xae, MV_WAVES);
    const float* cur = xA;
    float* nxt = xB;
    for (int l = 0; l < LL; l++) {
        const float* WmL = Wm + (size_t)l * 128 * 64;
        const float* WuL = Wu + (size_t)l * 128 * 64;
        k_layer_agg<<<2048, 256, 0, stream>>>(cur, off, cnt, sorted, xagg);
        // m = relu([xagg|xae] @ Wm + bm)  as two K=64 passes
        k_mv64<0><<<MV_BLOCKS, 256, 0, stream>>>(xagg, WmL, nullptr, nullptr, tmpb, MV_WAVES);
        k_mv64<1><<<MV_BLOCKS, 256, 0, stream>>>(xae, WmL + 64 * 64, bm + l * 64, tmpb,
                                                 mbuf, MV_WAVES);
        // x' = relu([xemb|m] @ Wu + bu)  as two K=64 passes
        k_mv64<0><<<MV_BLOCKS, 256, 0, stream>>>(cur, WuL, nullptr, nullptr, tmpb, MV_WAVES);
        k_mv64<1><<<MV_BLOCKS, 256, 0, stream>>>(mbuf, WuL + 64 * 64, bu + l * 64, tmpb,
                                                 nxt, MV_WAVES);
        float* t = (float*)cur; cur = nxt; nxt = t;
    }
    int gs_waves = (NN + CHUNK - 1) / CHUNK;
    k_graph_sum<<<(gs_waves * 64 + 255) / 256, 256, 0, stream>>>(cur, batch, g_sum, g_cnt);
    k_graph_emb<<<16, 256, 0, stream>>>(g_sum, g_cnt, W_g, b_g, g_agg);
    k_readout<<<(NN + 255) / 256, 256, 0, stream>>>(g_agg, cur, batch, W_r, b_r, out);
}

// Round 16
// 488.952 us; speedup vs baseline: 1.0786x; 1.0440x over previous
//
#include <hip/hip_runtime.h>

constexpr int NN  = 50000;
constexpr int EE  = 800000;
constexpr int GG  = 64;
constexpr int LL  = 3;

__device__ __forceinline__ float reluf(float x) { return x > 0.f ? x : 0.f; }

// -------- in-degree count; also record each edge's within-row rank -----------
__global__ void k_count(const int* __restrict__ ei, int* __restrict__ cnt,
                        int* __restrict__ rel) {
    int e = blockIdx.x * blockDim.x + threadIdx.x;
    if (e >= EE) return;
    rel[e] = atomicAdd(&cnt[ei[EE + e]], 1);
}

// ------- parallel exclusive scan (49 blocks x 1024) + fused per-graph degmax -
__global__ void k_scan1(const int* __restrict__ cnt, int* __restrict__ off,
                        int* __restrict__ bsum,
                        const int* __restrict__ batch, const float* __restrict__ degree,
                        unsigned* __restrict__ degmax_u) {
    __shared__ int s[256];
    __shared__ unsigned smax[GG];
    int t = threadIdx.x, blk = blockIdx.x;
    if (t < GG) smax[t] = 0u;
    int base = blk * 1024 + t * 4;
    int v[4], tot = 0;
#pragma unroll
    for (int j = 0; j < 4; j++) {
        int i = base + j;
        v[j] = (i < NN) ? cnt[i] : 0;
        tot += v[j];
    }
    s[t] = tot;
    __syncthreads();
    {
        int curb = -1; unsigned cur = 0u;
#pragma unroll
        for (int j = 0; j < 4; j++) {
            int i = base + j;
            if (i < NN) {
                int b = batch[i];
                unsigned d = __float_as_uint(degree[i]);  // degree >= 0
                if (b != curb) {
                    if (curb >= 0) atomicMax(&smax[curb], cur);
                    curb = b; cur = d;
                } else if (d > cur) cur = d;
            }
        }
        if (curb >= 0) atomicMax(&smax[curb], cur);
    }
    for (int d = 1; d < 256; d <<= 1) {
        int a = (t >= d) ? s[t - d] : 0;
        __syncthreads();
        s[t] += a;
        __syncthreads();
    }
    int run = s[t] - tot;
#pragma unroll
    for (int j = 0; j < 4; j++) {
        int i = base + j;
        if (i <= NN) off[i] = run;
        run += v[j];
    }
    if (t == 255) bsum[blk] = s[255];
    __syncthreads();
    if (t < GG && smax[t] != 0u) atomicMax(&degmax_u[t], smax[t]);
}
__global__ void k_scan2(int* __restrict__ bsum, int nb) {
    if (threadIdx.x == 0) {
        int run = 0;
        for (int b = 0; b < nb; b++) { int t = bsum[b]; bsum[b] = run; run += t; }
    }
}
__global__ void k_scan3(int* __restrict__ off, const int* __restrict__ bsum) {
    int i = blockIdx.x * blockDim.x + threadIdx.x;
    if (i <= NN) off[i] += bsum[i >> 10];
}

// ---------------- scatter edges into CSR order (atomic-free) -----------------
__global__ void k_fill(const int* __restrict__ ei, const float* __restrict__ ea,
                       const int* __restrict__ off, const int* __restrict__ rel,
                       int2* __restrict__ sorted) {
    int e = blockIdx.x * blockDim.x + threadIdx.x;
    if (e >= EE) return;
    int col = ei[e];
    int row = ei[EE + e];
    sorted[off[row] + rel[e]] = make_int2(col, __float_as_int(ea[e]));
}

// ---------------- ne_sum from CSR: 8 lanes per node, 4-way unroll ------------
__global__ void k_nesum(const float* __restrict__ x, const int2* __restrict__ sorted,
                        const int* __restrict__ off, float* __restrict__ ne_sum) {
    int gwave = (blockIdx.x * blockDim.x + threadIdx.x) >> 6;
    int lane = threadIdx.x & 63;
    int sub = lane >> 3;   // 8 nodes per wave
    int f = lane & 7;      // 8 features (7 x + 1 ea)
    int node = gwave * 8 + sub;
    if (node >= NN) return;
    int jb = off[node], je = off[node + 1];
    float a0 = 0.f, a1 = 0.f, a2 = 0.f, a3 = 0.f;
    int j = jb;
    for (; j + 4 <= je; j += 4) {
        int2 p0 = sorted[j], p1 = sorted[j + 1], p2 = sorted[j + 2], p3 = sorted[j + 3];
        a0 += (f < 7) ? x[(size_t)p0.x * 7 + f] : __int_as_float(p0.y);
        a1 += (f < 7) ? x[(size_t)p1.x * 7 + f] : __int_as_float(p1.y);
        a2 += (f < 7) ? x[(size_t)p2.x * 7 + f] : __int_as_float(p2.y);
        a3 += (f < 7) ? x[(size_t)p3.x * 7 + f] : __int_as_float(p3.y);
    }
    for (; j < je; j++) {
        int2 p = sorted[j];
        a0 += (f < 7) ? x[(size_t)p.x * 7 + f] : __int_as_float(p.y);
    }
    ne_sum[(size_t)node * 8 + f] = (a0 + a1) + (a2 + a3);
}

// ---------------- node pre: x_emb and agg_in = [relu(ne@W_ene+b), degnorm] ---
__global__ __launch_bounds__(256) void k_node_pre(
        const float* __restrict__ x, const int* __restrict__ cnt,
        const float* __restrict__ ne_sum, const unsigned* __restrict__ degmax_u,
        const int* __restrict__ batch,
        const float* __restrict__ W_en, const float* __restrict__ b_en,
        const float* __restrict__ W_ene, const float* __restrict__ b_ene,
        float* __restrict__ x_emb, float* __restrict__ agg_in) {
    __shared__ float sWen[7 * 64], sben[64];
    __shared__ float sWene[8 * 63], sbene[63];
    for (int i = threadIdx.x; i < 7 * 64; i += 256) sWen[i] = W_en[i];
    for (int i = threadIdx.x; i < 64; i += 256) sben[i] = b_en[i];
    for (int i = threadIdx.x; i < 8 * 63; i += 256) sWene[i] = W_ene[i];
    for (int i = threadIdx.x; i < 63; i += 256) sbene[i] = b_ene[i];
    __syncthreads();
    int lane = threadIdx.x & 63;
    int slot = threadIdx.x >> 6;
    int wave = blockIdx.x * 4 + slot;
    int nw = gridDim.x * 4;
    for (int i = wave; i < NN; i += nw) {
        float acc = sben[lane];
#pragma unroll
        for (int k = 0; k < 7; k++) acc += x[(size_t)i * 7 + k] * sWen[k * 64 + lane];
        x_emb[(size_t)i * 64 + lane] = reluf(acc);
        float c = (float)cnt[i]; if (c < 1.f) c = 1.f;
        float rc = 1.f / c;
        int oo = lane < 63 ? lane : 0;
        float na = sbene[oo];
#pragma unroll
        for (int k = 0; k < 8; k++) na += (ne_sum[(size_t)i * 8 + k] * rc) * sWene[k * 63 + oo];
        na = reluf(na);
        float dn = __uint_as_float(degmax_u[batch[i]]);
        agg_in[(size_t)i * 64 + lane] = (lane < 63) ? na : dn;
    }
}

// ---------------- half-K matvec pass with LDS-staged input (r13 proven) ------
// MODE 0: out = dot   MODE 1: out = relu(dot + tmp + b)   MODE 2: relu(dot + b)
template <int MODE>
__global__ __launch_bounds__(256) void k_mv64(
        const float* __restrict__ in, const float* __restrict__ W,
        const float* __restrict__ b, const float* __restrict__ tmp,
        float* __restrict__ out, int nwaves) {
    __shared__ float sbuf[4][2][64];
    int slot = threadIdx.x >> 6;
    int gwave = (blockIdx.x * blockDim.x + threadIdx.x) >> 6;
    int lane = threadIdx.x & 63;
    int per = (NN + nwaves - 1) / nwaves;
    int n0 = gwave * per;
    int n1 = n0 + per; if (n1 > NN) n1 = NN;
    if (n0 >= n1) return;
    float w[64];
#pragma unroll
    for (int k = 0; k < 64; k++) w[k] = W[(size_t)k * 64 + lane];
    float bias = (MODE == 0) ? 0.f : b[lane];
    sbuf[slot][0][lane] = in[(size_t)n0 * 64 + lane];
    int cntn = n1 - n0;
    for (int i = 0; i < cntn; i++) {
        int n = n0 + i;
        size_t oA = (size_t)n * 64 + lane;
        float tv = (MODE == 1) ? tmp[oA] : 0.f;
        float vnext = 0.f;
        if (i + 1 < cntn) vnext = in[(size_t)(n + 1) * 64 + lane];
        const float* bufp = &sbuf[slot][i & 1][0];
        float a0 = 0.f, a1 = 0.f;
#pragma unroll
        for (int kb = 0; kb < 64; kb += 8) {
            float4 x0 = *(const float4*)(bufp + kb);
            float4 x1 = *(const float4*)(bufp + kb + 4);
            a0 = fmaf(x0.x, w[kb + 0], a0); a1 = fmaf(x0.y, w[kb + 1], a1);
            a0 = fmaf(x0.z, w[kb + 2], a0); a1 = fmaf(x0.w, w[kb + 3], a1);
            a0 = fmaf(x1.x, w[kb + 4], a0); a1 = fmaf(x1.y, w[kb + 5], a1);
            a0 = fmaf(x1.z, w[kb + 6], a0); a1 = fmaf(x1.w, w[kb + 7], a1);
        }
        float r = a0 + a1;
        if (MODE == 0)      out[oA] = r;
        else if (MODE == 1) out[oA] = reluf(r + tv + bias);
        else                out[oA] = reluf(r + bias);
        if (i + 1 < cntn) sbuf[slot][(i + 1) & 1][lane] = vnext;
    }
}

// -------- layer aggregation: x_agg = mean_j ea_j * xemb[col_j] ---------------
// r6 unmasked 8-wide main chunks + ONE masked 8-slot tail chunk (clamped
// index -> duplicate L1-hit row, zeroed scale -> exact no-op). Removes the
// ~3.5 serial dependent gathers/node of the r6 scalar tail without r7's
// mistake of masking the hot main loop.
__global__ __launch_bounds__(256) void k_layer_agg(
        const float* __restrict__ xemb, const int* __restrict__ off,
        const int* __restrict__ cnt, const int2* __restrict__ sorted,
        float* __restrict__ xagg) {
    int lane = threadIdx.x & 63;
    int slot = threadIdx.x >> 6;
    int wave = blockIdx.x * 4 + slot;
    int nw = gridDim.x * 4;
    for (int i = wave; i < NN; i += nw) {
        int jb = off[i], je = off[i + 1];
        float a0 = 0.f, a1 = 0.f, a2 = 0.f, a3 = 0.f;
        float a4 = 0.f, a5 = 0.f, a6 = 0.f, a7 = 0.f;
        int j = jb;
        for (; j + 8 <= je; j += 8) {
            int2 p0 = sorted[j + 0], p1 = sorted[j + 1];
            int2 p2 = sorted[j + 2], p3 = sorted[j + 3];
            int2 p4 = sorted[j + 4], p5 = sorted[j + 5];
            int2 p6 = sorted[j + 6], p7 = sorted[j + 7];
            a0 = fmaf(__int_as_float(p0.y), xemb[(size_t)p0.x * 64 + lane], a0);
            a1 = fmaf(__int_as_float(p1.y), xemb[(size_t)p1.x * 64 + lane], a1);
            a2 = fmaf(__int_as_float(p2.y), xemb[(size_t)p2.x * 64 + lane], a2);
            a3 = fmaf(__int_as_float(p3.y), xemb[(size_t)p3.x * 64 + lane], a3);
            a4 = fmaf(__int_as_float(p4.y), xemb[(size_t)p4.x * 64 + lane], a4);
            a5 = fmaf(__int_as_float(p5.y), xemb[(size_t)p5.x * 64 + lane], a5);
            a6 = fmaf(__int_as_float(p6.y), xemb[(size_t)p6.x * 64 + lane], a6);
            a7 = fmaf(__int_as_float(p7.y), xemb[(size_t)p7.x * 64 + lane], a7);
        }
        if (j < je) {   // masked tail: 1-7 edges, all gathers independent
            int jl = je - 1;
            int2 p0 = sorted[j + 0];
            int2 p1 = sorted[min(j + 1, jl)];
            int2 p2 = sorted[min(j + 2, jl)];
            int2 p3 = sorted[min(j + 3, jl)];
            int2 p4 = sorted[min(j + 4, jl)];
            int2 p5 = sorted[min(j + 5, jl)];
            int2 p6 = sorted[min(j + 6, jl)];
            int2 p7 = sorted[min(j + 7, jl)];
            float s0 = __int_as_float(p0.y);
            float s1 = (j + 1 < je) ? __int_as_float(p1.y) : 0.f;
            float s2 = (j + 2 < je) ? __int_as_float(p2.y) : 0.f;
            float s3 = (j + 3 < je) ? __int_as_float(p3.y) : 0.f;
            float s4 = (j + 4 < je) ? __int_as_float(p4.y) : 0.f;
            float s5 = (j + 5 < je) ? __int_as_float(p5.y) : 0.f;
            float s6 = (j + 6 < je) ? __int_as_float(p6.y) : 0.f;
            float s7 = (j + 7 < je) ? __int_as_float(p7.y) : 0.f;
            a0 = fmaf(s0, xemb[(size_t)p0.x * 64 + lane], a0);
            a1 = fmaf(s1, xemb[(size_t)p1.x * 64 + lane], a1);
            a2 = fmaf(s2, xemb[(size_t)p2.x * 64 + lane], a2);
            a3 = fmaf(s3, xemb[(size_t)p3.x * 64 + lane], a3);
            a4 = fmaf(s4, xemb[(size_t)p4.x * 64 + lane], a4);
            a5 = fmaf(s5, xemb[(size_t)p5.x * 64 + lane], a5);
            a6 = fmaf(s6, xemb[(size_t)p6.x * 64 + lane], a6);
            a7 = fmaf(s7, xemb[(size_t)p7.x * 64 + lane], a7);
        }
        float acc = ((a0 + a1) + (a2 + a3)) + ((a4 + a5) + (a6 + a7));
        float c = (float)cnt[i]; if (c < 1.f) c = 1.f;
        xagg[(size_t)i * 64 + lane] = acc * (1.f / c);
    }
}

// ---------------- graph mean (batch sorted: chunked accumulation) ------------
constexpr int CHUNK = 32;
__global__ void k_graph_sum(const float* __restrict__ xemb, const int* __restrict__ batch,
                            float* __restrict__ g_sum, int* __restrict__ g_cnt) {
    int wave = (blockIdx.x * blockDim.x + threadIdx.x) >> 6;
    int lane = threadIdx.x & 63;
    int i0 = wave * CHUNK;
    if (i0 >= NN) return;
    int i1 = i0 + CHUNK; if (i1 > NN) i1 = NN;
    int curb = batch[i0];
    float acc = 0.f;
    int ncnt = 0;
    for (int i = i0; i < i1; i++) {
        int b = batch[i];
        if (b != curb) {
            unsafeAtomicAdd(&g_sum[curb * 64 + lane], acc);
            if (lane == 0) atomicAdd(&g_cnt[curb], ncnt);
            acc = 0.f; ncnt = 0; curb = b;
        }
        acc += xemb[(size_t)i * 64 + lane];
        ncnt++;
    }
    unsafeAtomicAdd(&g_sum[curb * 64 + lane], acc);
    if (lane == 0) atomicAdd(&g_cnt[curb], ncnt);
}

// ---------------- graph embedding: g_agg = mean @ W_g + b_g (no relu) --------
__global__ void k_graph_emb(const float* __restrict__ g_sum, const int* __restrict__ g_cnt,
                            const float* __restrict__ W_g, const float* __restrict__ b_g,
                            float* __restrict__ g_agg) {
    __shared__ float sin[4 * 64];
    int lane = threadIdx.x & 63;
    int slot = threadIdx.x >> 6;
    int g = blockIdx.x * 4 + slot;
    if (g >= GG) return;
    float c = (float)g_cnt[g]; if (c < 1.f) c = 1.f;
    sin[slot * 64 + lane] = g_sum[g * 64 + lane] * (1.f / c);
    __syncthreads();
    float acc = b_g[lane];
    for (int k = 0; k < 64; k++) acc += sin[slot * 64 + k] * W_g[k * 64 + lane];
    g_agg[g * 64 + lane] = acc;
}

// ---------------- readout: q = relu([g_agg[batch], x_emb]) @ W_r + b_r -------
__global__ void k_readout(const float* __restrict__ g_agg, const float* __restrict__ xemb,
                          const int* __restrict__ batch,
                          const float* __restrict__ W_r, const float* __restrict__ b_r,
                          float* __restrict__ out) {
    int i = blockIdx.x * blockDim.x + threadIdx.x;
    if (i >= NN) return;
    int b = batch[i];
    float acc = b_r[0];
    const float* ga = g_agg + (size_t)b * 64;
    const float* xe = xemb + (size_t)i * 64;
#pragma unroll 8
    for (int k = 0; k < 64; k++) acc += reluf(ga[k]) * W_r[k];
#pragma unroll 8
    for (int k = 0; k < 64; k++) acc += reluf(xe[k]) * W_r[64 + k];
    out[i] = acc;
}

extern "C" void kernel_launch(void* const* d_in, const int* in_sizes, int n_in,
                              void* d_out, int out_size, void* d_ws, size_t ws_size,
                              hipStream_t stream) {
    const float* x      = (const float*)d_in[0];
    const int*   ei     = (const int*)d_in[1];
    const float* ea     = (const float*)d_in[2];
    const int*   batch  = (const int*)d_in[3];
    const float* degree = (const float*)d_in[4];
    const float* W_en  = (const float*)d_in[6];
    const float* b_en  = (const float*)d_in[7];
    const float* W_ene = (const float*)d_in[8];
    const float* b_ene = (const float*)d_in[9];
    const float* W_agg = (const float*)d_in[10];
    const float* b_agg = (const float*)d_in[11];
    const float* Wm    = (const float*)d_in[12];
    const float* bm    = (const float*)d_in[13];
    const float* Wu    = (const float*)d_in[14];
    const float* bu    = (const float*)d_in[15];
    const float* W_g   = (const float*)d_in[16];
    const float* b_g   = (const float*)d_in[17];
    const float* W_r   = (const float*)d_in[18];
    const float* b_r   = (const float*)d_in[19];
    float* out = (float*)d_out;

    // workspace layout (4B element offsets); zeroed region first
    char* ws = (char*)d_ws;
    size_t o = 0;
    int*      cnt      = (int*)(ws + o * 4);      o += NN;
    unsigned* degmax_u = (unsigned*)(ws + o * 4); o += GG;
    float*    g_sum    = (float*)(ws + o * 4);    o += GG * 64;
    int*      g_cnt    = (int*)(ws + o * 4);      o += GG;
    size_t zero_bytes = o * 4;
    int*      off      = (int*)(ws + o * 4);      o += NN + 1;
    int*      bsum     = (int*)(ws + o * 4);      o += 64;
    int*      rel      = (int*)(ws + o * 4);      o += EE;
    float*    ne_sum   = (float*)(ws + o * 4);    o += (size_t)NN * 8;
    o = (o + 1) & ~(size_t)1;  // 8B-align for int2
    int2*     sorted   = (int2*)(ws + o * 4);     o += (size_t)EE * 2;
    float*    agg_in   = (float*)(ws + o * 4);    o += (size_t)NN * 64;
    float*    xae      = (float*)(ws + o * 4);    o += (size_t)NN * 64;
    float*    xA       = (float*)(ws + o * 4);    o += (size_t)NN * 64;
    float*    xB       = (float*)(ws + o * 4);    o += (size_t)NN * 64;
    float*    xagg     = (float*)(ws + o * 4);    o += (size_t)NN * 64;
    float*    mbuf     = (float*)(ws + o * 4);    o += (size_t)NN * 64;
    float*    tmpb     = (float*)(ws + o * 4);    o += (size_t)NN * 64;
    float*    g_agg    = (float*)(ws + o * 4);    o += GG * 64;

    hipMemsetAsync(d_ws, 0, zero_bytes, stream);

    const int NB_SCAN = 49;        // ceil(50001/1024)
    const int MV_BLOCKS = 1024;    // 4096 waves, ~13 nodes/wave (r13 proven)
    const int MV_WAVES = MV_BLOCKS * 4;
    k_count<<<(EE + 255) / 256, 256, 0, stream>>>(ei, cnt, rel);
    k_scan1<<<NB_SCAN, 256, 0, stream>>>(cnt, off, bsum, batch, degree, degmax_u);
    k_scan2<<<1, 64, 0, stream>>>(bsum, NB_SCAN);
    k_scan3<<<(NN + 256) / 256, 256, 0, stream>>>(off, bsum);
    k_fill<<<(EE + 255) / 256, 256, 0, stream>>>(ei, ea, off, rel, sorted);
    k_nesum<<<((NN + 7) / 8 * 64 + 255) / 256, 256, 0, stream>>>(x, sorted, off, ne_sum);
    k_node_pre<<<512, 256, 0, stream>>>(x, cnt, ne_sum, degmax_u, batch,
                                        W_en, b_en, W_ene, b_ene, xA, agg_in);
    // x_agg_emb = relu(agg_in @ W_agg + b_agg)   (K=64, standalone)
    k_mv64<2><<<MV_BLOCKS, 256, 0, stream>>>(agg_in, W_agg, b_agg, nullptr, xae, MV_WAVES);
    const float* cur = xA;
    float* nxt = xB;
    for (int l = 0; l < LL; l++) {
        const float* WmL = Wm + (size_t)l * 128 * 64;
        const float* WuL = Wu + (size_t)l * 128 * 64;
        k_layer_agg<<<2048, 256, 0, stream>>>(cur, off, cnt, sorted, xagg);
        // m = relu([xagg|xae] @ Wm + bm)  as two K=64 passes
        k_mv64<0><<<MV_BLOCKS, 256, 0, stream>>>(xagg, WmL, nullptr, nullptr, tmpb, MV_WAVES);
        k_mv64<1><<<MV_BLOCKS, 256, 0, stream>>>(xae, WmL + 64 * 64, bm + l * 64, tmpb,
                                                 mbuf, MV_WAVES);
        // x' = relu([xemb|m] @ Wu + bu)  as two K=64 passes
        k_mv64<0><<<MV_BLOCKS, 256, 0, stream>>>(cur, WuL, nullptr, nullptr, tmpb, MV_WAVES);
        k_mv64<1><<<MV_BLOCKS, 256, 0, stream>>>(mbuf, WuL + 64 * 64, bu + l * 64, tmpb,
                                                 nxt, MV_WAVES);
        float* t = (float*)cur; cur = nxt; nxt = t;
    }
    int gs_waves = (NN + CHUNK - 1) / CHUNK;
    k_graph_sum<<<(gs_waves * 64 + 255) / 256, 256, 0, stream>>>(cur, batch, g_sum, g_cnt);
    k_graph_emb<<<16, 256, 0, stream>>>(g_sum, g_cnt, W_g, b_g, g_agg);
    k_readout<<<(NN + 255) / 256, 256, 0, stream>>>(g_agg, cur, batch, W_r, b_r, out);
}